// Round 9
// baseline (1088.673 us; speedup 1.0000x reference)
//
#include <hip/hip_runtime.h>
#include <stdint.h>
#include <math.h>

// Problem constants (B=2,S=2048,H=1024,E=8,K=2,F=4096)
#define T_TOK 4096
#define H_DIM 1024
#define E_EXP 8
#define F_DIM 4096
#define NASSIGN (T_TOK * 2)
#define OUT_ELEMS ((size_t)T_TOK * H_DIM)
#define YB_ELEMS ((size_t)8192 * H_DIM)   // one split-K slab: [8192][H] f32
#define TL 257                            // LDS transpose row length (bank-tuned)

typedef unsigned short u16;
typedef __attribute__((ext_vector_type(8))) short short8;   // 8 bf16 = 4 VGPRs
typedef __attribute__((ext_vector_type(4))) short short4v;  // 4 bf16 = 2 VGPRs
typedef __attribute__((ext_vector_type(4))) float f32x4;

__device__ __forceinline__ u16 f2bf(float f) {
  union { float f; uint32_t u; } c; c.f = f;
  uint32_t u = c.u;
  return (u16)((u + 0x7FFFu + ((u >> 16) & 1u)) >> 16);  // RNE
}

// fast erf (Abramowitz-Stegun 7.1.26, |abs err| <= 1.5e-7)
__device__ __forceinline__ float fast_erf(float u) {
  const float au = fabsf(u);
  const float t = __builtin_amdgcn_rcpf(__builtin_fmaf(0.3275911f, au, 1.0f));
  float p = __builtin_fmaf(1.061405429f, t, -1.453152027f);
  p = __builtin_fmaf(p, t, 1.421413741f);
  p = __builtin_fmaf(p, t, -0.284496736f);
  p = __builtin_fmaf(p, t, 0.254829592f);
  p = p * t;
  const float y = __builtin_fmaf(-p, __expf(-au * au), 1.0f);
  return copysignf(y, u);
}

// async global->LDS, 16B per lane. LDS dest is wave-uniform base + lane*16.
__device__ __forceinline__ void gl_lds16(const void* g, void* l) {
  __builtin_amdgcn_global_load_lds(
      (const __attribute__((address_space(1))) uint32_t*)g,
      (__attribute__((address_space(3))) uint32_t*)(uintptr_t)l, 16, 0, 0);
}

// ---------------- transpose strip (used by prep for W1, by gemm1 for W2) ----------------
// out: [E][C/64][R/64][64][64] bf16, inner tile [c-local][r-local], r contiguous.
__device__ __forceinline__ void transpose_strip(
    const float* __restrict__ in, u16* __restrict__ out, int R, int C,
    int bx /*256-col strip*/, int by /*64-row tile*/, int bz, u16* tile) {
  const size_t eoff = (size_t)bz * R * C;
  const int wave = threadIdx.x >> 6, lane = threadIdx.x & 63;
  const float* inp = in + eoff + ((size_t)by * 64) * C + bx * 256;
#pragma unroll
  for (int p = 0; p < 16; ++p) {
    const int r = p * 4 + wave;
    const float4 v = *(const float4*)(inp + (size_t)r * C + lane * 4);
    u16* trow = tile + r * TL + lane * 4;
    trow[0] = f2bf(v.x); trow[1] = f2bf(v.y); trow[2] = f2bf(v.z); trow[3] = f2bf(v.w);
  }
  __syncthreads();
  const int cl = threadIdx.x >> 3;          // 0..31 (col within tile, +p*32)
  const int rg = (threadIdx.x & 7) * 8;     // row group
#pragma unroll
  for (int tx = 0; tx < 4; ++tx) {
    u16* op = out + (((size_t)bz * (C >> 6) + bx * 4 + tx) * (R >> 6) + by) * 4096;
#pragma unroll
    for (int p = 0; p < 2; ++p) {
      const int c = cl + p * 32;
      short8 o;
#pragma unroll
      for (int j = 0; j < 8; ++j) o[j] = (short)tile[(rg + j) * TL + tx * 64 + c];
      *(short8*)(op + c * 64 + rg) = o;
    }
  }
}

// ---------------- fused prep: router + W1 transpose ----------------
__global__ __launch_bounds__(256) void prep_kernel(
    const float* __restrict__ x, const float* __restrict__ Wr,
    const float* __restrict__ br, u16* __restrict__ xb,
    int* __restrict__ tki, float* __restrict__ tkw,
    int* __restrict__ counts, float* __restrict__ zsum,
    const float* __restrict__ W1, u16* __restrict__ w1t) {
  __shared__ u16 tile[64 * TL];
  __shared__ int lcnt[8];
  __shared__ float lzv[16];
  const int id = blockIdx.x;

  if (id >= 256) {
    const int q = id - 256;   // W1 [E][H][F]: R=H(K), C=F(N); 16 bx x 16 by x 8 e
    transpose_strip(W1, w1t, H_DIM, F_DIM, q & 15, (q >> 4) & 15, q >> 8, tile);
    return;
  }

  // ---- router: 16 tokens per block (4 waves x 4 tokens), float4 x loads ----
  const int wave = threadIdx.x >> 6;
  const int lane = threadIdx.x & 63;
  if (threadIdx.x < 8) lcnt[threadIdx.x] = 0;
  __syncthreads();
#pragma unroll
  for (int it = 0; it < 4; ++it) {
    const int t = id * 16 + wave * 4 + it;
    const float* xr = x + (size_t)t * H_DIM;
    u16* xbr = xb + (size_t)t * H_DIM;
    float acc[8];
#pragma unroll
    for (int e = 0; e < 8; ++e) acc[e] = 0.0f;
#pragma unroll
    for (int j = 0; j < 4; ++j) {
      const int h0 = j * 256 + lane * 4;
      const float4 xv = *(const float4*)(xr + h0);
      const float vv[4] = {xv.x, xv.y, xv.z, xv.w};
      short4v pk;
#pragma unroll
      for (int i = 0; i < 4; ++i) {
        pk[i] = (short)f2bf(vv[i]);
        const float4 w0 = *(const float4*)(Wr + (size_t)(h0 + i) * 8);
        const float4 w1 = *(const float4*)(Wr + (size_t)(h0 + i) * 8 + 4);
        acc[0] += vv[i] * w0.x; acc[1] += vv[i] * w0.y;
        acc[2] += vv[i] * w0.z; acc[3] += vv[i] * w0.w;
        acc[4] += vv[i] * w1.x; acc[5] += vv[i] * w1.y;
        acc[6] += vv[i] * w1.z; acc[7] += vv[i] * w1.w;
      }
      *(short4v*)(xbr + h0) = pk;
    }
#pragma unroll
    for (int e = 0; e < 8; ++e) {
      float v = acc[e];
#pragma unroll
      for (int s = 32; s > 0; s >>= 1) v += __shfl_xor(v, s);
      acc[e] = v;
    }
    if (lane == 0) {
      float l[8];
#pragma unroll
      for (int e = 0; e < 8; ++e) l[e] = acc[e] + br[e];
      float mx = l[0];
#pragma unroll
      for (int e = 1; e < 8; ++e) mx = fmaxf(mx, l[e]);
      float p[8], s = 0.0f;
#pragma unroll
      for (int e = 0; e < 8; ++e) { p[e] = __expf(l[e] - mx); s += p[e]; }
      int i0 = 0;
#pragma unroll
      for (int e = 1; e < 8; ++e) if (p[e] > p[i0]) i0 = e;
      int i1 = (i0 == 0) ? 1 : 0;
#pragma unroll
      for (int e = 0; e < 8; ++e) if (e != i1 && e != i0 && p[e] > p[i1]) i1 = e;
      const float ws = p[i0] + p[i1];
      tki[2 * t] = i0; tki[2 * t + 1] = i1;
      tkw[2 * t] = p[i0] / ws; tkw[2 * t + 1] = p[i1] / ws;
      atomicAdd(&lcnt[i0], 1);
      atomicAdd(&lcnt[i1], 1);
      lzv[wave * 4 + it] = mx + logf(s);
    }
  }
  __syncthreads();
  if (threadIdx.x < 8) {
    const int c = lcnt[threadIdx.x];
    if (c) atomicAdd(&counts[threadIdx.x], c);
  }
  if (threadIdx.x == 64) {
    float zs = 0.0f;
#pragma unroll
    for (int i = 0; i < 16; ++i) zs += lzv[i];
    atomicAdd(zsum, zs);
  }
}

// scatter + (block 0) loss. Per-wave ballot aggregation for cursor atomics.
__global__ void scatter_kernel(const int* __restrict__ tki, const float* __restrict__ tkw,
                               const int* __restrict__ counts, int* __restrict__ cursor,
                               int* __restrict__ perm, float* __restrict__ pw,
                               int* __restrict__ islot,
                               const float* __restrict__ zsum, float* __restrict__ out_loss) {
  int offs[8];
  {
    int a = 0;
#pragma unroll
    for (int e = 0; e < 8; ++e) { offs[e] = a; a += counts[e]; }
  }
  const int lane = threadIdx.x & 63;
  const int t = blockIdx.x * 256 + threadIdx.x;
#pragma unroll
  for (int k = 0; k < 2; ++k) {
    const int e = tki[2 * t + k];
    int slot = 0;
#pragma unroll
    for (int ee = 0; ee < 8; ++ee) {
      const unsigned long long mask = __ballot(e == ee);
      if (mask) {
        const int leader = __ffsll(mask) - 1;
        int b = 0;
        if (lane == leader) b = atomicAdd(&cursor[ee], (int)__popcll(mask));
        b = __shfl(b, leader);
        if (e == ee) {
          const int r = (int)__popcll(mask & ((1ull << lane) - 1ull));
          slot = offs[ee] + b + r;
        }
      }
    }
    perm[slot] = t;
    pw[slot] = tkw[2 * t + k];
    islot[2 * t + k] = slot;
  }
  if (blockIdx.x == 0 && threadIdx.x == 0) {
    float aux = 0.0f;
#pragma unroll
    for (int e = 0; e < 8; ++e) {
      const float d = (float)counts[e] / (float)NASSIGN - 0.125f;
      aux += d * d;
    }
    aux *= (1.0f / 8.0f);
    out_loss[0] = 0.01f * aux + 0.001f * (zsum[0] / (float)T_TOK);
  }
}

// ---------------- grouped GEMMs: 128x128 tile, 4 waves, B DIRECT-TO-REGISTER ----------------
// A (gathered rows, shared by all waves) stays LDS-staged (dbuf 2x16KB, XOR swizzle,
// proven conflict-free). B is wave-private (one 64x64 w-tile per wave): each B fragment
// is a clean per-lane 16B global load -> skip LDS entirely. LDS/block-K-step drops
// 144KB -> 48KB (375 B/MFMA); acc 4x4 = 64 AGPR -> ~150 unified regs -> 3 waves/SIMD.
// Raw s_barrier + counted vmcnt(12) (4 A-DMA + 8 B-loads in flight) so the compiler's
// B-register pipeline survives the barrier (r4-verified skeleton).
// id&7 = expert -> XCD affinity (keeps each expert's 256KB B n-panel hot in L2).

#define STAGEA(NB)                                                        \
  { _Pragma("unroll")                                                     \
    for (int l = 0; l < 4; ++l) {                                         \
      gl_lds16(ap[l], &smem[(NB) + ((size_t)tid + l * 256) * 8]);         \
      ap[l] += 64;                                                        \
    } }

#define LOADB(DST)                                                        \
  { _Pragma("unroll")                                                     \
    for (int j = 0; j < 4; ++j) {                                         \
      _Pragma("unroll")                                                   \
      for (int s = 0; s < 2; ++s)                                         \
        DST[j][s] = bgp[(j * 16 + lr) * 8 + s * 4 + q];                   \
    }                                                                     \
    bgp += 512; }

#define COMPUTE(NB, BC)                                                   \
  { const short8* Afr = (const short8*)(smem + (NB));                     \
    _Pragma("unroll")                                                     \
    for (int s = 0; s < 2; ++s) {                                         \
      const int qs = s ? qs1 : qs0;                                       \
      short8 a[4];                                                        \
      _Pragma("unroll")                                                   \
      for (int i = 0; i < 4; ++i) a[i] = Afr[(wm + i * 16 + lr) * 8 + qs];\
      _Pragma("unroll")                                                   \
      for (int i = 0; i < 4; ++i)                                         \
        _Pragma("unroll")                                                 \
        for (int j = 0; j < 4; ++j)                                       \
          acc[i][j] = __builtin_amdgcn_mfma_f32_16x16x32_bf16(            \
              a[i], BC[j][s], acc[i][j], 0, 0, 0);                        \
    } }

#define VWAIT12 asm volatile("s_waitcnt vmcnt(12)" ::: "memory");         \
                __builtin_amdgcn_sched_barrier(0);                        \
                __builtin_amdgcn_s_barrier();
#define VWAIT0  asm volatile("s_waitcnt vmcnt(0)" ::: "memory");          \
                __builtin_amdgcn_sched_barrier(0);                        \
                __builtin_amdgcn_s_barrier();

// h[slot][F] = gelu( xb[perm[slot]] @ W1t[e]^T + b1[e] )  (bf16 out)
// blocks >= 8192 do the W2 transpose (gemm1 never reads w2t; gemm2 is stream-ordered after).
__global__ __launch_bounds__(256, 3) void gemm1_kernel(
    const u16* __restrict__ xb, const u16* __restrict__ w1t,
    const float* __restrict__ b1, const int* __restrict__ perm,
    const int* __restrict__ cnts, u16* __restrict__ hbuf,
    const float* __restrict__ W2, u16* __restrict__ w2t) {
  __shared__ __align__(16) u16 smem[64 * TL];   // 32.9KB: A dbuf (2x8192) / transpose tile
  const int id = blockIdx.x;

  if (id >= 8192) {           // W2 [E][F][H]: R=F(K), C=H(N); 4 bx x 64 by x 8 e
    const int q = id - 8192;
    transpose_strip(W2, w2t, F_DIM, H_DIM, q & 3, (q >> 2) & 63, q >> 8, smem);
    return;
  }

  const int e = id & 7;               // XCD group
  const int wq = id >> 3;
  const int n0 = (wq & 31) << 7;      // 32 n-blocks
  const int m0 = (wq >> 5) << 7;      // m outer
  int cnt, off;
  {
    int a = 0, c = 0;
#pragma unroll
    for (int i = 0; i < 8; ++i) { const int ci = cnts[i]; if (i < e) a += ci; if (i == e) c = ci; }
    cnt = c; off = a;
  }
  if (m0 >= cnt) return;

  const int tid = threadIdx.x;
  const int rbase = tid >> 3;
  const int kc = ((tid & 7) ^ (rbase & 7)) * 8;

  const u16* ap[4];
#pragma unroll
  for (int l = 0; l < 4; ++l) {
    int ra = m0 + rbase + l * 32; if (ra > cnt - 1) ra = cnt - 1;
    ap[l] = xb + (size_t)perm[off + ra] * H_DIM + kc;
  }

  const int wave = tid >> 6, lane = tid & 63;
  const int wm = (wave >> 1) * 64;
  const int lr = lane & 15, q = lane >> 4;
  const int qs0 = q ^ (lr & 7), qs1 = (4 + q) ^ (lr & 7);

  // B base: this wave's 64x64 tile of w1t, k-tile 0
  const int nt = (n0 >> 6) + (wave & 1);
  const short8* bgp = (const short8*)(w1t +
      ((((size_t)e * (F_DIM >> 6) + nt) * (H_DIM >> 6)) << 12));

  f32x4 acc[4][4];
#pragma unroll
  for (int i = 0; i < 4; ++i)
#pragma unroll
    for (int j = 0; j < 4; ++j) acc[i][j] = (f32x4)0.0f;

  short8 bA[4][2], bB[4][2];
  STAGEA(0); LOADB(bA);                 // K-step 0

  for (int k0 = 0; k0 < (H_DIM >> 6); k0 += 2) {
    // half 1: prefetch k0+1 (always valid, NK even), compute k0 from buf0/bA
    STAGEA(8192); LOADB(bB);
    VWAIT12;
    COMPUTE(0, bA);
    __builtin_amdgcn_s_barrier();
    // half 2: prefetch k0+2 if any, compute k0+1 from buf1/bB
    if (k0 + 2 < (H_DIM >> 6)) {
      STAGEA(0); LOADB(bA);
      VWAIT12;
    } else {
      VWAIT0;
    }
    COMPUTE(8192, bB);
    __builtin_amdgcn_s_barrier();
  }

  // Epilogue: bias+gelu (fast erf) -> bf16 -> LDS (XOR col swizzle) -> 16B stores.
  const int wn = (wave & 1) * 64;
#pragma unroll
  for (int i = 0; i < 4; ++i) {
#pragma unroll
    for (int rr = 0; rr < 4; ++rr) {
      const int row = wm + i * 16 + q * 4 + rr;
#pragma unroll
      for (int j = 0; j < 4; ++j) {
        const int col = wn + j * 16 + lr;
        const float v = acc[i][j][rr] + b1[e * F_DIM + n0 + col];
        const float g = 0.5f * v * (1.0f + fast_erf(v * 0.70710678118654752f));
        smem[(row << 7) + (col ^ (q << 4))] = f2bf(g);
      }
    }
  }
  __syncthreads();
#pragma unroll
  for (int p = 0; p < 8; ++p) {
    const int ml = p * 16 + (tid >> 4);
    const int nl = (tid & 15) * 8;
    const int m = m0 + ml;
    if (m < cnt) {
      const int qq = (ml >> 2) & 3;
      *(short8*)(hbuf + (size_t)(off + m) * F_DIM + n0 + nl) =
          *(const short8*)(smem + (ml << 7) + (nl ^ (qq << 4)));
    }
  }
}

// ybuf[ks][slot] = w_slot * (h[slot] @ W2t[e]^T [k-half ks] + (ks==0)*b2[e])
__global__ __launch_bounds__(256, 3) void gemm2_kernel(
    const u16* __restrict__ hbuf, const u16* __restrict__ w2t,
    const float* __restrict__ b2, const float* __restrict__ pw,
    const int* __restrict__ cnts, float* __restrict__ ybuf) {
  __shared__ __align__(16) u16 smem[16384];   // A dbuf 2x16KB
  const int id = blockIdx.x;
  const int e = id & 7;               // XCD group
  const int wq = id >> 3;
  const int n0 = (wq & 7) << 7;       // 8 n-blocks
  const int ks = (wq >> 3) & 1;       // 2 K-splits (2048 each)
  const int m0 = (wq >> 4) << 7;      // m outer
  int cnt, off;
  {
    int a = 0, c = 0;
#pragma unroll
    for (int i = 0; i < 8; ++i) { const int ci = cnts[i]; if (i < e) a += ci; if (i == e) c = ci; }
    cnt = c; off = a;
  }
  if (m0 >= cnt) return;

  const int tid = threadIdx.x;
  const int rbase = tid >> 3;
  const int kc = ((tid & 7) ^ (rbase & 7)) * 8;

  const u16* ap[4];
#pragma unroll
  for (int l = 0; l < 4; ++l) {
    int ra = m0 + rbase + l * 32; if (ra > cnt - 1) ra = cnt - 1;
    ap[l] = hbuf + (size_t)(off + ra) * F_DIM + (ks << 11) + kc;
  }

  const int wave = tid >> 6, lane = tid & 63;
  const int wm = (wave >> 1) * 64;
  const int lr = lane & 15, q = lane >> 4;
  const int qs0 = q ^ (lr & 7), qs1 = (4 + q) ^ (lr & 7);

  const int nt = (n0 >> 6) + (wave & 1);
  const short8* bgp = (const short8*)(w2t +
      (((size_t)e * (H_DIM >> 6) + nt) * (F_DIM >> 6) + (ks << 5)) * 4096);

  f32x4 acc[4][4];
#pragma unroll
  for (int i = 0; i < 4; ++i)
#pragma unroll
    for (int j = 0; j < 4; ++j) acc[i][j] = (f32x4)0.0f;

  short8 bA[4][2], bB[4][2];
  STAGEA(0); LOADB(bA);

  for (int k0 = 0; k0 < 32; k0 += 2) {   // 2048/64
    STAGEA(8192); LOADB(bB);
    VWAIT12;
    COMPUTE(0, bA);
    __builtin_amdgcn_s_barrier();
    if (k0 + 2 < 32) {
      STAGEA(0); LOADB(bA);
      VWAIT12;
    } else {
      VWAIT0;
    }
    COMPUTE(8192, bB);
    __builtin_amdgcn_s_barrier();
  }

  // Epilogue: per-slot weighted partial, plain f32 stores into slab ks.
  const int wn = (wave & 1) * 64;
  float* yb = ybuf + (size_t)ks * YB_ELEMS;
#pragma unroll
  for (int i = 0; i < 4; ++i) {
#pragma unroll
    for (int rr = 0; rr < 4; ++rr) {
      const int m = m0 + wm + i * 16 + q * 4 + rr;
      if (m < cnt) {
        const int slot = off + m;
        const float w = pw[slot];
        float* orow = yb + (size_t)slot * H_DIM;
#pragma unroll
        for (int j = 0; j < 4; ++j) {
          const int col = n0 + wn + j * 16 + lr;
          float y = acc[i][j][rr];
          if (ks == 0) y += b2[e * H_DIM + col];
          orow[col] = w * y;
        }
      }
    }
  }
}

// out[t] = sum over k of (ybuf0[slot_k] + ybuf1[slot_k])
__global__ __launch_bounds__(256) void combine_kernel(
    const float* __restrict__ ybuf, const int* __restrict__ islot,
    float* __restrict__ out) {
  const int t = blockIdx.x;
  const int s0 = islot[2 * t];
  const int s1 = islot[2 * t + 1];
  const int c = threadIdx.x * 4;
  const float4 a0 = *(const float4*)(ybuf + (size_t)s0 * H_DIM + c);
  const float4 a1 = *(const float4*)(ybuf + YB_ELEMS + (size_t)s0 * H_DIM + c);
  const float4 b0 = *(const float4*)(ybuf + (size_t)s1 * H_DIM + c);
  const float4 b1 = *(const float4*)(ybuf + YB_ELEMS + (size_t)s1 * H_DIM + c);
  float4 r;
  r.x = a0.x + a1.x + b0.x + b1.x;
  r.y = a0.y + a1.y + b0.y + b1.y;
  r.z = a0.z + a1.z + b0.z + b1.z;
  r.w = a0.w + a1.w + b0.w + b1.w;
  *(float4*)(out + (size_t)t * H_DIM + c) = r;
}

// ---------------- launch ----------------

extern "C" void kernel_launch(void* const* d_in, const int* in_sizes, int n_in,
                              void* d_out, int out_size, void* d_ws, size_t ws_size,
                              hipStream_t stream) {
  const float* x  = (const float*)d_in[0];
  const float* Wr = (const float*)d_in[1];
  const float* br = (const float*)d_in[2];
  const float* W1 = (const float*)d_in[3];
  const float* b1 = (const float*)d_in[4];
  const float* W2 = (const float*)d_in[5];
  const float* b2 = (const float*)d_in[6];
  float* out = (float*)d_out;

  // workspace layout (~210 MB)
  char* ws = (char*)d_ws;
  u16* xb    = (u16*)(ws);                          // 8 MB
  u16* w1t   = (u16*)(ws + 8388608ull);             // 64 MB  tiled [E][F/64][H/64][64][64]
  u16* w2t   = (u16*)(ws + 75497472ull);            // 64 MB  tiled [E][H/64][F/64][64][64]
  u16* hbuf  = (u16*)(ws + 142606336ull);           // 64 MB  [8192][F] bf16
  // ybuf reuses w1t's 64MB region: w1t is dead after gemm1, ybuf written by gemm2.
  float* ybuf = (float*)(ws + 8388608ull);          // 64 MB  2 slabs of [8192][H] f32
  int*   tki    = (int*)(ws + 209715200ull);
  float* tkw    = (float*)(ws + 209747968ull);
  int*   perm   = (int*)(ws + 209780736ull);
  float* pw     = (float*)(ws + 209813504ull);
  int*   counts = (int*)(ws + 209846272ull);        // counts[8], cursor[8], zsum
  int*   cursor = counts + 8;
  float* zsum   = (float*)(counts + 16);
  int*   islot  = (int*)(ws + 209846400ull);        // 32 KB  [T][2] slot map

  hipMemsetAsync(counts, 0, 128, stream);

  // prep: router (0..255) + W1 strips (256..2303). W2 transpose rides inside gemm1.
  prep_kernel<<<2304, 256, 0, stream>>>(x, Wr, br, xb, tki, tkw, counts, zsum, W1, w1t);
  scatter_kernel<<<T_TOK / 256, 256, 0, stream>>>(tki, tkw, counts, cursor, perm, pw,
                                                  islot, zsum, out + OUT_ELEMS);
  // gemm1: 8192 gemm blocks + 2048 W2-transpose strips (ids >= 8192)
  gemm1_kernel<<<10240, 256, 0, stream>>>(xb, w1t, b1, perm, counts, hbuf, W2, w2t);
  // 8 experts x 8 n-blocks x 2 K-splits x up to 32 m-blocks
  gemm2_kernel<<<4096, 256, 0, stream>>>(hbuf, w2t, b2, pw, counts, ybuf);
  combine_kernel<<<T_TOK, 256, 0, stream>>>(ybuf, islot, out);
}

// Round 10
// 571.418 us; speedup vs baseline: 1.9052x; 1.9052x over previous
//
#include <hip/hip_runtime.h>
#include <stdint.h>
#include <math.h>

// Problem constants (B=2,S=2048,H=1024,E=8,K=2,F=4096)
#define T_TOK 4096
#define H_DIM 1024
#define E_EXP 8
#define F_DIM 4096
#define NASSIGN (T_TOK * 2)
#define OUT_ELEMS ((size_t)T_TOK * H_DIM)
#define YB_ELEMS ((size_t)8192 * H_DIM)   // one split-K slab: [8192][H] f32
#define TL 257                            // LDS transpose row length (bank-tuned)

typedef unsigned short u16;
typedef __attribute__((ext_vector_type(8))) short short8;   // 8 bf16 = 4 VGPRs
typedef __attribute__((ext_vector_type(4))) short short4v;  // 4 bf16 = 2 VGPRs
typedef __attribute__((ext_vector_type(4))) float f32x4;

__device__ __forceinline__ u16 f2bf(float f) {
  union { float f; uint32_t u; } c; c.f = f;
  uint32_t u = c.u;
  return (u16)((u + 0x7FFFu + ((u >> 16) & 1u)) >> 16);  // RNE
}

// fast erf (Abramowitz-Stegun 7.1.26, |abs err| <= 1.5e-7)
__device__ __forceinline__ float fast_erf(float u) {
  const float au = fabsf(u);
  const float t = __builtin_amdgcn_rcpf(__builtin_fmaf(0.3275911f, au, 1.0f));
  float p = __builtin_fmaf(1.061405429f, t, -1.453152027f);
  p = __builtin_fmaf(p, t, 1.421413741f);
  p = __builtin_fmaf(p, t, -0.284496736f);
  p = __builtin_fmaf(p, t, 0.254829592f);
  p = p * t;
  const float y = __builtin_fmaf(-p, __expf(-au * au), 1.0f);
  return copysignf(y, u);
}

// async global->LDS, 16B per lane. LDS dest is wave-uniform base + lane*16.
__device__ __forceinline__ void gl_lds16(const void* g, void* l) {
  __builtin_amdgcn_global_load_lds(
      (const __attribute__((address_space(1))) uint32_t*)g,
      (__attribute__((address_space(3))) uint32_t*)(uintptr_t)l, 16, 0, 0);
}

// ---------------- transpose strip (prep: W1; gemm1 tail blocks: W2) ----------------
// out: [E][C/64][R/64][64][64] bf16, inner tile [c-local][r-local], r contiguous.
__device__ __forceinline__ void transpose_strip(
    const float* __restrict__ in, u16* __restrict__ out, int R, int C,
    int bx /*256-col strip*/, int by /*64-row tile*/, int bz, u16* tile) {
  const size_t eoff = (size_t)bz * R * C;
  const int wave = threadIdx.x >> 6, lane = threadIdx.x & 63;
  const float* inp = in + eoff + ((size_t)by * 64) * C + bx * 256;
#pragma unroll
  for (int p = 0; p < 16; ++p) {
    const int r = p * 4 + wave;
    const float4 v = *(const float4*)(inp + (size_t)r * C + lane * 4);
    u16* trow = tile + r * TL + lane * 4;
    trow[0] = f2bf(v.x); trow[1] = f2bf(v.y); trow[2] = f2bf(v.z); trow[3] = f2bf(v.w);
  }
  __syncthreads();
  const int cl = threadIdx.x >> 3;          // 0..31 (col within tile, +p*32)
  const int rg = (threadIdx.x & 7) * 8;     // row group
#pragma unroll
  for (int tx = 0; tx < 4; ++tx) {
    u16* op = out + (((size_t)bz * (C >> 6) + bx * 4 + tx) * (R >> 6) + by) * 4096;
#pragma unroll
    for (int p = 0; p < 2; ++p) {
      const int c = cl + p * 32;
      short8 o;
#pragma unroll
      for (int j = 0; j < 8; ++j) o[j] = (short)tile[(rg + j) * TL + tx * 64 + c];
      *(short8*)(op + c * 64 + rg) = o;
    }
  }
}

// ---------------- fused prep: router + W1 transpose ----------------
__global__ __launch_bounds__(256) void prep_kernel(
    const float* __restrict__ x, const float* __restrict__ Wr,
    const float* __restrict__ br, u16* __restrict__ xb,
    int* __restrict__ tki, float* __restrict__ tkw,
    int* __restrict__ counts, float* __restrict__ zsum,
    const float* __restrict__ W1, u16* __restrict__ w1t) {
  __shared__ u16 tile[64 * TL];
  __shared__ int lcnt[8];
  __shared__ float lzv[16];
  const int id = blockIdx.x;

  if (id >= 256) {
    const int q = id - 256;   // W1 [E][H][F]: R=H(K), C=F(N); 16 bx x 16 by x 8 e
    transpose_strip(W1, w1t, H_DIM, F_DIM, q & 15, (q >> 4) & 15, q >> 8, tile);
    return;
  }

  // ---- router: 16 tokens per block (4 waves x 4 tokens), float4 x loads ----
  const int wave = threadIdx.x >> 6;
  const int lane = threadIdx.x & 63;
  if (threadIdx.x < 8) lcnt[threadIdx.x] = 0;
  __syncthreads();
#pragma unroll
  for (int it = 0; it < 4; ++it) {
    const int t = id * 16 + wave * 4 + it;
    const float* xr = x + (size_t)t * H_DIM;
    u16* xbr = xb + (size_t)t * H_DIM;
    float acc[8];
#pragma unroll
    for (int e = 0; e < 8; ++e) acc[e] = 0.0f;
#pragma unroll
    for (int j = 0; j < 4; ++j) {
      const int h0 = j * 256 + lane * 4;
      const float4 xv = *(const float4*)(xr + h0);
      const float vv[4] = {xv.x, xv.y, xv.z, xv.w};
      short4v pk;
#pragma unroll
      for (int i = 0; i < 4; ++i) {
        pk[i] = (short)f2bf(vv[i]);
        const float4 w0 = *(const float4*)(Wr + (size_t)(h0 + i) * 8);
        const float4 w1 = *(const float4*)(Wr + (size_t)(h0 + i) * 8 + 4);
        acc[0] += vv[i] * w0.x; acc[1] += vv[i] * w0.y;
        acc[2] += vv[i] * w0.z; acc[3] += vv[i] * w0.w;
        acc[4] += vv[i] * w1.x; acc[5] += vv[i] * w1.y;
        acc[6] += vv[i] * w1.z; acc[7] += vv[i] * w1.w;
      }
      *(short4v*)(xbr + h0) = pk;
    }
#pragma unroll
    for (int e = 0; e < 8; ++e) {
      float v = acc[e];
#pragma unroll
      for (int s = 32; s > 0; s >>= 1) v += __shfl_xor(v, s);
      acc[e] = v;
    }
    if (lane == 0) {
      float l[8];
#pragma unroll
      for (int e = 0; e < 8; ++e) l[e] = acc[e] + br[e];
      float mx = l[0];
#pragma unroll
      for (int e = 1; e < 8; ++e) mx = fmaxf(mx, l[e]);
      float p[8], s = 0.0f;
#pragma unroll
      for (int e = 0; e < 8; ++e) { p[e] = __expf(l[e] - mx); s += p[e]; }
      int i0 = 0;
#pragma unroll
      for (int e = 1; e < 8; ++e) if (p[e] > p[i0]) i0 = e;
      int i1 = (i0 == 0) ? 1 : 0;
#pragma unroll
      for (int e = 0; e < 8; ++e) if (e != i1 && e != i0 && p[e] > p[i1]) i1 = e;
      const float ws = p[i0] + p[i1];
      tki[2 * t] = i0; tki[2 * t + 1] = i1;
      tkw[2 * t] = p[i0] / ws; tkw[2 * t + 1] = p[i1] / ws;
      atomicAdd(&lcnt[i0], 1);
      atomicAdd(&lcnt[i1], 1);
      lzv[wave * 4 + it] = mx + logf(s);
    }
  }
  __syncthreads();
  if (threadIdx.x < 8) {
    const int c = lcnt[threadIdx.x];
    if (c) atomicAdd(&counts[threadIdx.x], c);
  }
  if (threadIdx.x == 64) {
    float zs = 0.0f;
#pragma unroll
    for (int i = 0; i < 16; ++i) zs += lzv[i];
    atomicAdd(zsum, zs);
  }
}

// scatter + (block 0) loss. Per-wave ballot aggregation for cursor atomics.
__global__ void scatter_kernel(const int* __restrict__ tki, const float* __restrict__ tkw,
                               const int* __restrict__ counts, int* __restrict__ cursor,
                               int* __restrict__ perm, float* __restrict__ pw,
                               int* __restrict__ islot,
                               const float* __restrict__ zsum, float* __restrict__ out_loss) {
  int offs[8];
  {
    int a = 0;
#pragma unroll
    for (int e = 0; e < 8; ++e) { offs[e] = a; a += counts[e]; }
  }
  const int lane = threadIdx.x & 63;
  const int t = blockIdx.x * 256 + threadIdx.x;
#pragma unroll
  for (int k = 0; k < 2; ++k) {
    const int e = tki[2 * t + k];
    int slot = 0;
#pragma unroll
    for (int ee = 0; ee < 8; ++ee) {
      const unsigned long long mask = __ballot(e == ee);
      if (mask) {
        const int leader = __ffsll(mask) - 1;
        int b = 0;
        if (lane == leader) b = atomicAdd(&cursor[ee], (int)__popcll(mask));
        b = __shfl(b, leader);
        if (e == ee) {
          const int r = (int)__popcll(mask & ((1ull << lane) - 1ull));
          slot = offs[ee] + b + r;
        }
      }
    }
    perm[slot] = t;
    pw[slot] = tkw[2 * t + k];
    islot[2 * t + k] = slot;
  }
  if (blockIdx.x == 0 && threadIdx.x == 0) {
    float aux = 0.0f;
#pragma unroll
    for (int e = 0; e < 8; ++e) {
      const float d = (float)counts[e] / (float)NASSIGN - 0.125f;
      aux += d * d;
    }
    aux *= (1.0f / 8.0f);
    out_loss[0] = 0.01f * aux + 0.001f * (zsum[0] / (float)T_TOK);
  }
}

// ---------------- grouped GEMMs: 256x128 tile, wave tile 128x64, BK=64 ----------------
// (round-8 structure -- best measured. r9's B-in-register variant spilled to
// scratch: WRITE_SIZE 80MB->685MB. Keep A+B LDS-staged, gl_lds DMA.)
// id&7 = expert -> XCD affinity.

// h[slot][F] = gelu( xb[perm[slot]] @ W1t[e]^T + b1[e] )  (bf16 out)
// blocks >= 4096 do the W2 transpose (gemm1 never reads w2t; gemm2 stream-ordered after).
__global__ __launch_bounds__(256, 2) void gemm1_kernel(
    const u16* __restrict__ xb, const u16* __restrict__ w1t,
    const float* __restrict__ b1, const int* __restrict__ perm,
    const int* __restrict__ cnts, u16* __restrict__ hbuf,
    const float* __restrict__ W2, u16* __restrict__ w2t) {
  __shared__ __align__(16) u16 smem[24576];   // As 32KB (256x64) + Bs 16KB (128x64); transpose tile fits
  const int id = blockIdx.x;

  if (id >= 4096) {           // W2 [E][F][H]: R=F(K), C=H(N); 4 bx x 64 by x 8 e
    const int q = id - 4096;
    transpose_strip(W2, w2t, F_DIM, H_DIM, q & 3, (q >> 2) & 63, q >> 8, smem);
    return;
  }

  u16* As = smem;
  u16* Bs = smem + 16384;

  const int e = id & 7;               // XCD group
  const int wq = id >> 3;
  const int n0 = (wq & 31) << 7;      // 32 n-blocks of 128
  const int m0 = (wq >> 5) << 8;      // 16 m-slots of 256; live blocks first
  int cnt, off;
  {
    int a = 0, c = 0;
#pragma unroll
    for (int i = 0; i < 8; ++i) { const int ci = cnts[i]; if (i < e) a += ci; if (i == e) c = ci; }
    cnt = c; off = a;
  }
  if (m0 >= cnt) return;

  const int tid = threadIdx.x;
  const int rbase = tid >> 3;
  const int kc = ((tid & 7) ^ (rbase & 7)) * 8;

  const u16* ap[8];
#pragma unroll
  for (int l = 0; l < 8; ++l) {
    int ra = m0 + rbase + l * 32; if (ra > cnt - 1) ra = cnt - 1;
    ap[l] = xb + (size_t)perm[off + ra] * H_DIM + kc;
  }
  const u16* bp0 = w1t + ((((size_t)e * (F_DIM >> 6) + (n0 >> 6)) * (H_DIM >> 6)) << 12)
                 + rbase * 64 + kc;
  const size_t bnt = (size_t)(H_DIM >> 6) << 12;

  const int wave = tid >> 6, lane = tid & 63;
  const int wm = (wave >> 1) * 128, wn = (wave & 1) * 64;
  const int lr = lane & 15, q = lane >> 4;
  const int qs0 = q ^ (lr & 7), qs1 = (4 + q) ^ (lr & 7);

  f32x4 acc[8][4];
#pragma unroll
  for (int i = 0; i < 8; ++i)
#pragma unroll
    for (int j = 0; j < 4; ++j) acc[i][j] = (f32x4)0.0f;

  const short8* Afr = (const short8*)As;
  const short8* Bfr = (const short8*)Bs;

  for (int k0 = 0; k0 < (H_DIM >> 6); ++k0) {
#pragma unroll
    for (int l = 0; l < 8; ++l) {
      gl_lds16(ap[l], &As[(size_t)(tid + l * 256) * 8]);
      ap[l] += 64;
    }
    gl_lds16(bp0,              &Bs[(size_t)tid * 8]);
    gl_lds16(bp0 + 2048,       &Bs[(size_t)(tid + 256) * 8]);
    gl_lds16(bp0 + bnt,        &Bs[(size_t)(tid + 512) * 8]);
    gl_lds16(bp0 + bnt + 2048, &Bs[(size_t)(tid + 768) * 8]);
    bp0 += 4096;
    __syncthreads();
#pragma unroll
    for (int s = 0; s < 2; ++s) {
      const int qs = s ? qs1 : qs0;
      short8 a[8], b[4];
#pragma unroll
      for (int i = 0; i < 8; ++i) a[i] = Afr[(wm + i * 16 + lr) * 8 + qs];
#pragma unroll
      for (int j = 0; j < 4; ++j) b[j] = Bfr[(wn + j * 16 + lr) * 8 + qs];
#pragma unroll
      for (int i = 0; i < 8; ++i)
#pragma unroll
        for (int j = 0; j < 4; ++j)
          acc[i][j] = __builtin_amdgcn_mfma_f32_16x16x32_bf16(a[i], b[j], acc[i][j], 0, 0, 0);
    }
    __syncthreads();
  }

  // Epilogue: two 128-row passes through 32KB of smem (proven swizzle).
#pragma unroll
  for (int h = 0; h < 2; ++h) {
    if ((wave >> 1) == h) {
#pragma unroll
      for (int i = 0; i < 8; ++i) {
#pragma unroll
        for (int rr = 0; rr < 4; ++rr) {
          const int rloc = i * 16 + q * 4 + rr;     // 0..127
#pragma unroll
          for (int j = 0; j < 4; ++j) {
            const int col = wn + j * 16 + lr;       // 0..127
            const float v = acc[i][j][rr] + b1[e * F_DIM + n0 + col];
            const float g = 0.5f * v * (1.0f + fast_erf(v * 0.70710678118654752f));
            smem[(rloc << 7) + (col ^ (q << 4))] = f2bf(g);
          }
        }
      }
    }
    __syncthreads();
#pragma unroll
    for (int p = 0; p < 8; ++p) {
      const int ml = p * 16 + (tid >> 4);
      const int nl = (tid & 15) * 8;
      const int m = m0 + h * 128 + ml;
      if (m < cnt) {
        const int qq = (ml >> 2) & 3;
        *(short8*)(hbuf + (size_t)(off + m) * F_DIM + n0 + nl) =
            *(const short8*)(smem + (ml << 7) + (nl ^ (qq << 4)));
      }
    }
    __syncthreads();
  }
}

// ybuf[ks][slot] = w_slot * (h[slot] @ W2t[e]^T [k-half ks] + (ks==0)*b2[e])
// split-K=2 over separate slabs -> no atomics.
__global__ __launch_bounds__(256, 2) void gemm2_kernel(
    const u16* __restrict__ hbuf, const u16* __restrict__ w2t,
    const float* __restrict__ b2, const float* __restrict__ pw,
    const int* __restrict__ cnts, float* __restrict__ ybuf) {
  const int id = blockIdx.x;
  const int e = id & 7;               // XCD group
  const int wq = id >> 3;
  const int n0 = (wq & 7) << 7;       // 8 n-blocks of 128
  const int ks = (wq >> 3) & 1;       // 2 K-splits (2048 each)
  const int m0 = (wq >> 4) << 8;      // 16 m-slots of 256
  int cnt, off;
  {
    int a = 0, c = 0;
#pragma unroll
    for (int i = 0; i < 8; ++i) { const int ci = cnts[i]; if (i < e) a += ci; if (i == e) c = ci; }
    cnt = c; off = a;
  }
  if (m0 >= cnt) return;

  __shared__ __align__(16) u16 smem[24576];   // As 256x64 + Bs 128x64
  u16* As = smem;
  u16* Bs = smem + 16384;

  const int tid = threadIdx.x;
  const int rbase = tid >> 3;
  const int kc = ((tid & 7) ^ (rbase & 7)) * 8;

  const u16* ap[8];
#pragma unroll
  for (int l = 0; l < 8; ++l) {
    int ra = m0 + rbase + l * 32; if (ra > cnt - 1) ra = cnt - 1;
    ap[l] = hbuf + (size_t)(off + ra) * F_DIM + (ks << 11) + kc;
  }
  const u16* bp0 = w2t + ((((size_t)e * (H_DIM >> 6) + (n0 >> 6)) * (F_DIM >> 6)) << 12)
                 + ((size_t)(ks << 5) << 12) + rbase * 64 + kc;
  const size_t bnt = (size_t)(F_DIM >> 6) << 12;

  const int wave = tid >> 6, lane = tid & 63;
  const int wm = (wave >> 1) * 128, wn = (wave & 1) * 64;
  const int lr = lane & 15, q = lane >> 4;
  const int qs0 = q ^ (lr & 7), qs1 = (4 + q) ^ (lr & 7);

  f32x4 acc[8][4];
#pragma unroll
  for (int i = 0; i < 8; ++i)
#pragma unroll
    for (int j = 0; j < 4; ++j) acc[i][j] = (f32x4)0.0f;

  const short8* Afr = (const short8*)As;
  const short8* Bfr = (const short8*)Bs;

  for (int k0 = 0; k0 < 32; ++k0) {   // 2048 / 64, half of K
#pragma unroll
    for (int l = 0; l < 8; ++l) {
      gl_lds16(ap[l], &As[(size_t)(tid + l * 256) * 8]);
      ap[l] += 64;
    }
    gl_lds16(bp0,              &Bs[(size_t)tid * 8]);
    gl_lds16(bp0 + 2048,       &Bs[(size_t)(tid + 256) * 8]);
    gl_lds16(bp0 + bnt,        &Bs[(size_t)(tid + 512) * 8]);
    gl_lds16(bp0 + bnt + 2048, &Bs[(size_t)(tid + 768) * 8]);
    bp0 += 4096;
    __syncthreads();
#pragma unroll
    for (int s = 0; s < 2; ++s) {
      const int qs = s ? qs1 : qs0;
      short8 a[8], b[4];
#pragma unroll
      for (int i = 0; i < 8; ++i) a[i] = Afr[(wm + i * 16 + lr) * 8 + qs];
#pragma unroll
      for (int j = 0; j < 4; ++j) b[j] = Bfr[(wn + j * 16 + lr) * 8 + qs];
#pragma unroll
      for (int i = 0; i < 8; ++i)
#pragma unroll
        for (int j = 0; j < 4; ++j)
          acc[i][j] = __builtin_amdgcn_mfma_f32_16x16x32_bf16(a[i], b[j], acc[i][j], 0, 0, 0);
    }
    __syncthreads();
  }

  // Epilogue: per-slot weighted partial, plain f32 stores into slab ks.
  float* yb = ybuf + (size_t)ks * YB_ELEMS;
#pragma unroll
  for (int i = 0; i < 8; ++i) {
#pragma unroll
    for (int rr = 0; rr < 4; ++rr) {
      const int m = m0 + wm + i * 16 + q * 4 + rr;
      if (m < cnt) {
        const int slot = off + m;
        const float w = pw[slot];
        float* orow = yb + (size_t)slot * H_DIM;
#pragma unroll
        for (int j = 0; j < 4; ++j) {
          const int col = n0 + wn + j * 16 + lr;
          float y = acc[i][j][rr];
          if (ks == 0) y += b2[e * H_DIM + col];
          orow[col] = w * y;
        }
      }
    }
  }
}

// out[t] = sum over k of (ybuf0[slot_k] + ybuf1[slot_k])
__global__ __launch_bounds__(256) void combine_kernel(
    const float* __restrict__ ybuf, const int* __restrict__ islot,
    float* __restrict__ out) {
  const int t = blockIdx.x;
  const int s0 = islot[2 * t];
  const int s1 = islot[2 * t + 1];
  const int c = threadIdx.x * 4;
  const float4 a0 = *(const float4*)(ybuf + (size_t)s0 * H_DIM + c);
  const float4 a1 = *(const float4*)(ybuf + YB_ELEMS + (size_t)s0 * H_DIM + c);
  const float4 b0 = *(const float4*)(ybuf + (size_t)s1 * H_DIM + c);
  const float4 b1 = *(const float4*)(ybuf + YB_ELEMS + (size_t)s1 * H_DIM + c);
  float4 r;
  r.x = a0.x + a1.x + b0.x + b1.x;
  r.y = a0.y + a1.y + b0.y + b1.y;
  r.z = a0.z + a1.z + b0.z + b1.z;
  r.w = a0.w + a1.w + b0.w + b1.w;
  *(float4*)(out + (size_t)t * H_DIM + c) = r;
}

// ---------------- launch ----------------

extern "C" void kernel_launch(void* const* d_in, const int* in_sizes, int n_in,
                              void* d_out, int out_size, void* d_ws, size_t ws_size,
                              hipStream_t stream) {
  const float* x  = (const float*)d_in[0];
  const float* Wr = (const float*)d_in[1];
  const float* br = (const float*)d_in[2];
  const float* W1 = (const float*)d_in[3];
  const float* b1 = (const float*)d_in[4];
  const float* W2 = (const float*)d_in[5];
  const float* b2 = (const float*)d_in[6];
  float* out = (float*)d_out;

  // workspace layout (~210 MB)
  char* ws = (char*)d_ws;
  u16* xb    = (u16*)(ws);                          // 8 MB
  u16* w1t   = (u16*)(ws + 8388608ull);             // 64 MB  tiled [E][F/64][H/64][64][64]
  u16* w2t   = (u16*)(ws + 75497472ull);            // 64 MB  tiled [E][H/64][F/64][64][64]
  u16* hbuf  = (u16*)(ws + 142606336ull);           // 64 MB  [8192][F] bf16
  // ybuf reuses w1t's 64MB region: w1t is dead after gemm1, ybuf written by gemm2.
  float* ybuf = (float*)(ws + 8388608ull);          // 64 MB  2 slabs of [8192][H] f32
  int*   tki    = (int*)(ws + 209715200ull);
  float* tkw    = (float*)(ws + 209747968ull);
  int*   perm   = (int*)(ws + 209780736ull);
  float* pw     = (float*)(ws + 209813504ull);
  int*   counts = (int*)(ws + 209846272ull);        // counts[8], cursor[8], zsum
  int*   cursor = counts + 8;
  float* zsum   = (float*)(counts + 16);
  int*   islot  = (int*)(ws + 209846400ull);        // 32 KB  [T][2] slot map

  hipMemsetAsync(counts, 0, 128, stream);

  // prep: router (0..255) + W1 strips (256..2303). W2 transpose rides inside gemm1.
  prep_kernel<<<2304, 256, 0, stream>>>(x, Wr, br, xb, tki, tkw, counts, zsum, W1, w1t);
  scatter_kernel<<<T_TOK / 256, 256, 0, stream>>>(tki, tkw, counts, cursor, perm, pw,
                                                  islot, zsum, out + OUT_ELEMS);
  // gemm1: 4096 gemm blocks (8e x 32n x 16m) + 2048 W2-transpose strips (ids >= 4096)
  gemm1_kernel<<<6144, 256, 0, stream>>>(xb, w1t, b1, perm, counts, hbuf, W2, w2t);
  // 8 experts x 8 n-blocks x 2 K-splits x 16 m-slots
  gemm2_kernel<<<2048, 256, 0, stream>>>(hbuf, w2t, b2, pw, counts, ybuf);
  combine_kernel<<<T_TOK, 256, 0, stream>>>(ybuf, islot, out);
}

// Round 11
// 547.471 us; speedup vs baseline: 1.9885x; 1.0437x over previous
//
#include <hip/hip_runtime.h>
#include <stdint.h>
#include <math.h>

// Problem constants (B=2,S=2048,H=1024,E=8,K=2,F=4096)
#define T_TOK 4096
#define H_DIM 1024
#define E_EXP 8
#define F_DIM 4096
#define NASSIGN (T_TOK * 2)
#define OUT_ELEMS ((size_t)T_TOK * H_DIM)
#define YB_ELEMS ((size_t)8192 * H_DIM)   // one split-K slab: [8192][H] f32
#define TL 257                            // LDS transpose row length (bank-tuned)

typedef unsigned short u16;
typedef __attribute__((ext_vector_type(8))) short short8;   // 8 bf16 = 4 VGPRs
typedef __attribute__((ext_vector_type(4))) short short4v;  // 4 bf16 = 2 VGPRs
typedef __attribute__((ext_vector_type(4))) float f32x4;

__device__ __forceinline__ u16 f2bf(float f) {
  union { float f; uint32_t u; } c; c.f = f;
  uint32_t u = c.u;
  return (u16)((u + 0x7FFFu + ((u >> 16) & 1u)) >> 16);  // RNE
}

// fast erf (Abramowitz-Stegun 7.1.26, |abs err| <= 1.5e-7)
__device__ __forceinline__ float fast_erf(float u) {
  const float au = fabsf(u);
  const float t = __builtin_amdgcn_rcpf(__builtin_fmaf(0.3275911f, au, 1.0f));
  float p = __builtin_fmaf(1.061405429f, t, -1.453152027f);
  p = __builtin_fmaf(p, t, 1.421413741f);
  p = __builtin_fmaf(p, t, -0.284496736f);
  p = __builtin_fmaf(p, t, 0.254829592f);
  p = p * t;
  const float y = __builtin_fmaf(-p, __expf(-au * au), 1.0f);
  return copysignf(y, u);
}

// async global->LDS, 16B per lane. LDS dest is wave-uniform base + lane*16.
__device__ __forceinline__ void gl_lds16(const void* g, void* l) {
  __builtin_amdgcn_global_load_lds(
      (const __attribute__((address_space(1))) uint32_t*)g,
      (__attribute__((address_space(3))) uint32_t*)(uintptr_t)l, 16, 0, 0);
}

// ---------------- transpose strips ----------------
// out: [E][C/64][R/64][64][64] bf16, inner tile [c-local][r-local], r contiguous.
__device__ __forceinline__ void transpose_strip(
    const float* __restrict__ in, u16* __restrict__ out, int R, int C,
    int bx, int by, int bz, u16* tile) {     // 256 threads
  const size_t eoff = (size_t)bz * R * C;
  const int wave = threadIdx.x >> 6, lane = threadIdx.x & 63;
  const float* inp = in + eoff + ((size_t)by * 64) * C + bx * 256;
#pragma unroll
  for (int p = 0; p < 16; ++p) {
    const int r = p * 4 + wave;
    const float4 v = *(const float4*)(inp + (size_t)r * C + lane * 4);
    u16* trow = tile + r * TL + lane * 4;
    trow[0] = f2bf(v.x); trow[1] = f2bf(v.y); trow[2] = f2bf(v.z); trow[3] = f2bf(v.w);
  }
  __syncthreads();
  const int cl = threadIdx.x >> 3;
  const int rg = (threadIdx.x & 7) * 8;
#pragma unroll
  for (int tx = 0; tx < 4; ++tx) {
    u16* op = out + (((size_t)bz * (C >> 6) + bx * 4 + tx) * (R >> 6) + by) * 4096;
#pragma unroll
    for (int p = 0; p < 2; ++p) {
      const int c = cl + p * 32;
      short8 o;
#pragma unroll
      for (int j = 0; j < 8; ++j) o[j] = (short)tile[(rg + j) * TL + tx * 64 + c];
      *(short8*)(op + c * 64 + rg) = o;
    }
  }
}

__device__ __forceinline__ void transpose_strip512(
    const float* __restrict__ in, u16* __restrict__ out, int R, int C,
    int bx, int by, int bz, u16* tile) {     // 512 threads
  const size_t eoff = (size_t)bz * R * C;
  const int wv = threadIdx.x >> 6, lane = threadIdx.x & 63;
  const float* inp = in + eoff + ((size_t)by * 64) * C + bx * 256;
#pragma unroll
  for (int p = 0; p < 8; ++p) {
    const int r = p * 8 + wv;
    const float4 v = *(const float4*)(inp + (size_t)r * C + lane * 4);
    u16* trow = tile + r * TL + lane * 4;
    trow[0] = f2bf(v.x); trow[1] = f2bf(v.y); trow[2] = f2bf(v.z); trow[3] = f2bf(v.w);
  }
  __syncthreads();
  const int c = threadIdx.x >> 3;           // 0..63
  const int rg = (threadIdx.x & 7) * 8;
#pragma unroll
  for (int tx = 0; tx < 4; ++tx) {
    u16* op = out + (((size_t)bz * (C >> 6) + bx * 4 + tx) * (R >> 6) + by) * 4096;
    short8 o;
#pragma unroll
    for (int j = 0; j < 8; ++j) o[j] = (short)tile[(rg + j) * TL + tx * 64 + c];
    *(short8*)(op + c * 64 + rg) = o;
  }
}

// ---------------- fused prep: router + W1 transpose ----------------
__global__ __launch_bounds__(256) void prep_kernel(
    const float* __restrict__ x, const float* __restrict__ Wr,
    const float* __restrict__ br, u16* __restrict__ xb,
    int* __restrict__ tki, float* __restrict__ tkw,
    int* __restrict__ counts, float* __restrict__ zsum,
    const float* __restrict__ W1, u16* __restrict__ w1t) {
  __shared__ u16 tile[64 * TL];
  __shared__ int lcnt[8];
  __shared__ float lzv[16];
  const int id = blockIdx.x;

  if (id >= 256) {
    const int q = id - 256;   // W1 [E][H][F]: R=H(K), C=F(N); 16 bx x 16 by x 8 e
    transpose_strip(W1, w1t, H_DIM, F_DIM, q & 15, (q >> 4) & 15, q >> 8, tile);
    return;
  }

  // ---- router: 16 tokens per block (4 waves x 4 tokens), float4 x loads ----
  const int wave = threadIdx.x >> 6;
  const int lane = threadIdx.x & 63;
  if (threadIdx.x < 8) lcnt[threadIdx.x] = 0;
  __syncthreads();
#pragma unroll
  for (int it = 0; it < 4; ++it) {
    const int t = id * 16 + wave * 4 + it;
    const float* xr = x + (size_t)t * H_DIM;
    u16* xbr = xb + (size_t)t * H_DIM;
    float acc[8];
#pragma unroll
    for (int e = 0; e < 8; ++e) acc[e] = 0.0f;
#pragma unroll
    for (int j = 0; j < 4; ++j) {
      const int h0 = j * 256 + lane * 4;
      const float4 xv = *(const float4*)(xr + h0);
      const float vv[4] = {xv.x, xv.y, xv.z, xv.w};
      short4v pk;
#pragma unroll
      for (int i = 0; i < 4; ++i) {
        pk[i] = (short)f2bf(vv[i]);
        const float4 w0 = *(const float4*)(Wr + (size_t)(h0 + i) * 8);
        const float4 w1 = *(const float4*)(Wr + (size_t)(h0 + i) * 8 + 4);
        acc[0] += vv[i] * w0.x; acc[1] += vv[i] * w0.y;
        acc[2] += vv[i] * w0.z; acc[3] += vv[i] * w0.w;
        acc[4] += vv[i] * w1.x; acc[5] += vv[i] * w1.y;
        acc[6] += vv[i] * w1.z; acc[7] += vv[i] * w1.w;
      }
      *(short4v*)(xbr + h0) = pk;
    }
#pragma unroll
    for (int e = 0; e < 8; ++e) {
      float v = acc[e];
#pragma unroll
      for (int s = 32; s > 0; s >>= 1) v += __shfl_xor(v, s);
      acc[e] = v;
    }
    if (lane == 0) {
      float l[8];
#pragma unroll
      for (int e = 0; e < 8; ++e) l[e] = acc[e] + br[e];
      float mx = l[0];
#pragma unroll
      for (int e = 1; e < 8; ++e) mx = fmaxf(mx, l[e]);
      float p[8], s = 0.0f;
#pragma unroll
      for (int e = 0; e < 8; ++e) { p[e] = __expf(l[e] - mx); s += p[e]; }
      int i0 = 0;
#pragma unroll
      for (int e = 1; e < 8; ++e) if (p[e] > p[i0]) i0 = e;
      int i1 = (i0 == 0) ? 1 : 0;
#pragma unroll
      for (int e = 0; e < 8; ++e) if (e != i1 && e != i0 && p[e] > p[i1]) i1 = e;
      const float ws = p[i0] + p[i1];
      tki[2 * t] = i0; tki[2 * t + 1] = i1;
      tkw[2 * t] = p[i0] / ws; tkw[2 * t + 1] = p[i1] / ws;
      atomicAdd(&lcnt[i0], 1);
      atomicAdd(&lcnt[i1], 1);
      lzv[wave * 4 + it] = mx + logf(s);
    }
  }
  __syncthreads();
  if (threadIdx.x < 8) {
    const int c = lcnt[threadIdx.x];
    if (c) atomicAdd(&counts[threadIdx.x], c);
  }
  if (threadIdx.x == 64) {
    float zs = 0.0f;
#pragma unroll
    for (int i = 0; i < 16; ++i) zs += lzv[i];
    atomicAdd(zsum, zs);
  }
}

// scatter + (block 0) loss. Per-wave ballot aggregation for cursor atomics.
__global__ void scatter_kernel(const int* __restrict__ tki, const float* __restrict__ tkw,
                               const int* __restrict__ counts, int* __restrict__ cursor,
                               int* __restrict__ perm, float* __restrict__ pw,
                               int* __restrict__ islot,
                               const float* __restrict__ zsum, float* __restrict__ out_loss) {
  int offs[8];
  {
    int a = 0;
#pragma unroll
    for (int e = 0; e < 8; ++e) { offs[e] = a; a += counts[e]; }
  }
  const int lane = threadIdx.x & 63;
  const int t = blockIdx.x * 256 + threadIdx.x;
#pragma unroll
  for (int k = 0; k < 2; ++k) {
    const int e = tki[2 * t + k];
    int slot = 0;
#pragma unroll
    for (int ee = 0; ee < 8; ++ee) {
      const unsigned long long mask = __ballot(e == ee);
      if (mask) {
        const int leader = __ffsll(mask) - 1;
        int b = 0;
        if (lane == leader) b = atomicAdd(&cursor[ee], (int)__popcll(mask));
        b = __shfl(b, leader);
        if (e == ee) {
          const int r = (int)__popcll(mask & ((1ull << lane) - 1ull));
          slot = offs[ee] + b + r;
        }
      }
    }
    perm[slot] = t;
    pw[slot] = tkw[2 * t + k];
    islot[2 * t + k] = slot;
  }
  if (blockIdx.x == 0 && threadIdx.x == 0) {
    float aux = 0.0f;
#pragma unroll
    for (int e = 0; e < 8; ++e) {
      const float d = (float)counts[e] / (float)NASSIGN - 0.125f;
      aux += d * d;
    }
    aux *= (1.0f / 8.0f);
    out_loss[0] = 0.01f * aux + 0.001f * (zsum[0] / (float)T_TOK);
  }
}

// ---------------- grouped GEMMs: 256x256 tile, 8 waves, 4-phase interleaved schedule ----------------
// Layout/swizzle/addressing = r3's refcheck-passed 256^2 kernel. Schedule = T3/T4/T5:
// per K-tile, 4 phases (phase j = one C-column-quadrant, 16 MFMA); each phase
// {ds_read subtile -> stage-next chunk -> setprio(1) MFMA setprio(0) -> raw barrier};
// ONE vmcnt(0) per K-tile at tile start (waits loads issued a full K-tile earlier,
// ~620cy of cover). LDS: A dbuf 2x32KB @0, B dbuf 2x32KB @32768 (u16 idx). 128KB/block.

#define G_STAGE_A(NB)                                                        \
  { _Pragma("unroll")                                                        \
    for (int l = 0; l < 4; ++l) {                                            \
      gl_lds16(ap[l], &smem[(NB) + l * 4096 + tid * 8]); ap[l] += 64;        \
    } }

#define G_STAGE_B(NB)                                                        \
  { _Pragma("unroll")                                                        \
    for (int l = 0; l < 4; ++l) {                                            \
      gl_lds16(bp[l], &smem[32768 + (NB) + l * 4096 + tid * 8]); bp[l] += 4096; \
    } }

#define PH_BARRIER                                                           \
  asm volatile("" ::: "memory");                                             \
  __builtin_amdgcn_s_barrier();                                              \
  asm volatile("" ::: "memory");

#define MFMA_J(J)                                                            \
  { _Pragma("unroll")                                                        \
    for (int i = 0; i < 8; ++i) {                                            \
      acc[i][J] = __builtin_amdgcn_mfma_f32_16x16x32_bf16(a0[i], bj0, acc[i][J], 0, 0, 0); \
      acc[i][J] = __builtin_amdgcn_mfma_f32_16x16x32_bf16(a1[i], bj1, acc[i][J], 0, 0, 0); \
    } }

#define KLOOP(NKT)                                                           \
  for (int kt = 0; kt < (NKT); ++kt) {                                       \
    const int cb = (kt & 1) << 14;                                           \
    const int nb = 16384 - cb;                                               \
    const short8* Afr = (const short8*)(smem + cb);                          \
    const short8* Bfr = (const short8*)(smem + 32768 + cb);                  \
    asm volatile("s_waitcnt vmcnt(0)" ::: "memory");                         \
    __builtin_amdgcn_sched_barrier(0);                                       \
    __builtin_amdgcn_s_barrier();                                            \
    asm volatile("" ::: "memory");                                           \
    short8 a0[8], a1[8], bj0, bj1;                                           \
    _Pragma("unroll")                                                        \
    for (int i = 0; i < 8; ++i) {                                            \
      a0[i] = Afr[(wm + i * 16 + lr) * 8 + qs0];                             \
      a1[i] = Afr[(wm + i * 16 + lr) * 8 + qs1];                             \
    }                                                                        \
    bj0 = Bfr[(wn + lr) * 8 + qs0];                                          \
    bj1 = Bfr[(wn + lr) * 8 + qs1];                                          \
    if (kt + 1 < (NKT)) { G_STAGE_A(nb) }                                    \
    __builtin_amdgcn_s_setprio(1);                                           \
    MFMA_J(0)                                                                \
    __builtin_amdgcn_s_setprio(0);                                           \
    PH_BARRIER                                                               \
    bj0 = Bfr[(wn + 16 + lr) * 8 + qs0];                                     \
    bj1 = Bfr[(wn + 16 + lr) * 8 + qs1];                                     \
    if (kt + 1 < (NKT)) { G_STAGE_B(nb) }                                    \
    __builtin_amdgcn_s_setprio(1);                                           \
    MFMA_J(1)                                                                \
    __builtin_amdgcn_s_setprio(0);                                           \
    PH_BARRIER                                                               \
    bj0 = Bfr[(wn + 32 + lr) * 8 + qs0];                                     \
    bj1 = Bfr[(wn + 32 + lr) * 8 + qs1];                                     \
    __builtin_amdgcn_s_setprio(1);                                           \
    MFMA_J(2)                                                                \
    __builtin_amdgcn_s_setprio(0);                                           \
    PH_BARRIER                                                               \
    bj0 = Bfr[(wn + 48 + lr) * 8 + qs0];                                     \
    bj1 = Bfr[(wn + 48 + lr) * 8 + qs1];                                     \
    __builtin_amdgcn_s_setprio(1);                                           \
    MFMA_J(3)                                                                \
    __builtin_amdgcn_s_setprio(0);                                           \
    PH_BARRIER                                                               \
  }

// h[slot][F] = gelu( xb[perm[slot]] @ W1t[e]^T + b1[e] )  (bf16 out)
// blocks >= 2048 do the W2 transpose (gemm1 never reads w2t; gemm2 stream-ordered after).
__global__ __launch_bounds__(512, 2) void gemm1_kernel(
    const u16* __restrict__ xb, const u16* __restrict__ w1t,
    const float* __restrict__ b1, const int* __restrict__ perm,
    const int* __restrict__ cnts, u16* __restrict__ hbuf,
    const float* __restrict__ W2, u16* __restrict__ w2t) {
  __shared__ __align__(16) u16 smem[65536];   // 128KB: A/B dbuf; epilogue [256][256]
  const int id = blockIdx.x;

  if (id >= 2048) {           // W2 [E][F][H]: R=F(K), C=H(N); 4 bx x 64 by x 8 e
    const int q = id - 2048;
    transpose_strip512(W2, w2t, F_DIM, H_DIM, q & 3, (q >> 2) & 63, q >> 8, smem);
    return;
  }

  const int e = id & 7;               // XCD group
  const int wq = id >> 3;
  const int n0 = (wq & 15) << 8;      // 16 n-blocks of 256
  const int m0 = (wq >> 4) << 8;      // 16 m-slots of 256
  int cnt, off;
  {
    int a = 0, c = 0;
#pragma unroll
    for (int i = 0; i < 8; ++i) { const int ci = cnts[i]; if (i < e) a += ci; if (i == e) c = ci; }
    cnt = c; off = a;
  }
  if (m0 >= cnt) return;

  const int tid = threadIdx.x;
  const int rbase = tid >> 3;                    // 0..63
  const int kc = ((tid & 7) ^ (rbase & 7)) * 8;  // swizzled source chunk

  const u16* ap[4];
#pragma unroll
  for (int l = 0; l < 4; ++l) {
    int ra = m0 + rbase + l * 64; if (ra > cnt - 1) ra = cnt - 1;
    ap[l] = xb + (size_t)perm[off + ra] * H_DIM + kc;
  }
  const u16* bp[4];
#pragma unroll
  for (int l = 0; l < 4; ++l)
    bp[l] = w1t + (((size_t)e * (F_DIM >> 6) + (n0 >> 6) + l) * (H_DIM >> 6)) * 4096
          + rbase * 64 + kc;

  const int wave = tid >> 6, lane = tid & 63;
  const int wm = (wave >> 2) * 128, wn = (wave & 3) * 64;
  const int lr = lane & 15, q = lane >> 4;
  const int qs0 = q ^ (lr & 7), qs1 = (4 + q) ^ (lr & 7);

  f32x4 acc[8][4];
#pragma unroll
  for (int i = 0; i < 8; ++i)
#pragma unroll
    for (int j = 0; j < 4; ++j) acc[i][j] = (f32x4)0.0f;

  // prologue: stage K-tile 0 into buf 0
  G_STAGE_A(0)
  G_STAGE_B(0)

  KLOOP(H_DIM >> 6)

  // Epilogue: bias+gelu -> bf16 -> LDS [256][256] (XOR col swizzle) -> 16B stores.
#pragma unroll
  for (int i = 0; i < 8; ++i) {
#pragma unroll
    for (int rr = 0; rr < 4; ++rr) {
      const int row = wm + i * 16 + q * 4 + rr;
#pragma unroll
      for (int j = 0; j < 4; ++j) {
        const int col = wn + j * 16 + lr;
        const float v = acc[i][j][rr] + b1[e * F_DIM + n0 + col];
        const float g = 0.5f * v * (1.0f + fast_erf(v * 0.70710678118654752f));
        smem[(row << 8) + (col ^ (q << 4))] = f2bf(g);
      }
    }
  }
  __syncthreads();
#pragma unroll
  for (int p = 0; p < 16; ++p) {
    const int row = p * 16 + (tid >> 5);
    const int nl = (tid & 31) * 8;
    const int m = m0 + row;
    if (m < cnt) {
      const int qq = (row >> 2) & 3;
      *(short8*)(hbuf + (size_t)(off + m) * F_DIM + n0 + nl) =
          *(const short8*)(smem + (row << 8) + (nl ^ (qq << 4)));
    }
  }
}

// ybuf[ks][slot] = w_slot * (h[slot] @ W2t[e]^T [k-half ks] + (ks==0)*b2[e])
__global__ __launch_bounds__(512, 2) void gemm2_kernel(
    const u16* __restrict__ hbuf, const u16* __restrict__ w2t,
    const float* __restrict__ b2, const float* __restrict__ pw,
    const int* __restrict__ cnts, float* __restrict__ ybuf) {
  __shared__ __align__(16) u16 smem[65536];
  const int id = blockIdx.x;
  const int e = id & 7;               // XCD group
  const int wq = id >> 3;
  const int n0 = (wq & 3) << 8;       // 4 n-blocks of 256
  const int ks = (wq >> 2) & 1;       // 2 K-splits (2048 each)
  const int m0 = (wq >> 3) << 8;      // 16 m-slots
  int cnt, off;
  {
    int a = 0, c = 0;
#pragma unroll
    for (int i = 0; i < 8; ++i) { const int ci = cnts[i]; if (i < e) a += ci; if (i == e) c = ci; }
    cnt = c; off = a;
  }
  if (m0 >= cnt) return;

  const int tid = threadIdx.x;
  const int rbase = tid >> 3;
  const int kc = ((tid & 7) ^ (rbase & 7)) * 8;

  const u16* ap[4];
#pragma unroll
  for (int l = 0; l < 4; ++l) {
    int ra = m0 + rbase + l * 64; if (ra > cnt - 1) ra = cnt - 1;
    ap[l] = hbuf + (size_t)(off + ra) * F_DIM + (ks << 11) + kc;
  }
  const u16* bp[4];
#pragma unroll
  for (int l = 0; l < 4; ++l)
    bp[l] = w2t + (((size_t)e * (H_DIM >> 6) + (n0 >> 6) + l) * (F_DIM >> 6)
                   + (ks << 5)) * 4096 + rbase * 64 + kc;

  const int wave = tid >> 6, lane = tid & 63;
  const int wm = (wave >> 2) * 128, wn = (wave & 3) * 64;
  const int lr = lane & 15, q = lane >> 4;
  const int qs0 = q ^ (lr & 7), qs1 = (4 + q) ^ (lr & 7);

  f32x4 acc[8][4];
#pragma unroll
  for (int i = 0; i < 8; ++i)
#pragma unroll
    for (int j = 0; j < 4; ++j) acc[i][j] = (f32x4)0.0f;

  G_STAGE_A(0)
  G_STAGE_B(0)

  KLOOP(32)

  // Epilogue: per-slot weighted partial, plain f32 stores into slab ks.
  float* yb = ybuf + (size_t)ks * YB_ELEMS;
#pragma unroll
  for (int i = 0; i < 8; ++i) {
#pragma unroll
    for (int rr = 0; rr < 4; ++rr) {
      const int m = m0 + wm + i * 16 + q * 4 + rr;
      if (m < cnt) {
        const int slot = off + m;
        const float w = pw[slot];
        float* orow = yb + (size_t)slot * H_DIM;
#pragma unroll
        for (int j = 0; j < 4; ++j) {
          const int col = n0 + wn + j * 16 + lr;
          float y = acc[i][j][rr];
          if (ks == 0) y += b2[e * H_DIM + col];
          orow[col] = w * y;
        }
      }
    }
  }
}

// out[t] = sum over k of (ybuf0[slot_k] + ybuf1[slot_k])
__global__ __launch_bounds__(256) void combine_kernel(
    const float* __restrict__ ybuf, const int* __restrict__ islot,
    float* __restrict__ out) {
  const int t = blockIdx.x;
  const int s0 = islot[2 * t];
  const int s1 = islot[2 * t + 1];
  const int c = threadIdx.x * 4;
  const float4 a0 = *(const float4*)(ybuf + (size_t)s0 * H_DIM + c);
  const float4 a1 = *(const float4*)(ybuf + YB_ELEMS + (size_t)s0 * H_DIM + c);
  const float4 b0 = *(const float4*)(ybuf + (size_t)s1 * H_DIM + c);
  const float4 b1 = *(const float4*)(ybuf + YB_ELEMS + (size_t)s1 * H_DIM + c);
  float4 r;
  r.x = a0.x + a1.x + b0.x + b1.x;
  r.y = a0.y + a1.y + b0.y + b1.y;
  r.z = a0.z + a1.z + b0.z + b1.z;
  r.w = a0.w + a1.w + b0.w + b1.w;
  *(float4*)(out + (size_t)t * H_DIM + c) = r;
}

// ---------------- launch ----------------

extern "C" void kernel_launch(void* const* d_in, const int* in_sizes, int n_in,
                              void* d_out, int out_size, void* d_ws, size_t ws_size,
                              hipStream_t stream) {
  const float* x  = (const float*)d_in[0];
  const float* Wr = (const float*)d_in[1];
  const float* br = (const float*)d_in[2];
  const float* W1 = (const float*)d_in[3];
  const float* b1 = (const float*)d_in[4];
  const float* W2 = (const float*)d_in[5];
  const float* b2 = (const float*)d_in[6];
  float* out = (float*)d_out;

  // workspace layout (~210 MB)
  char* ws = (char*)d_ws;
  u16* xb    = (u16*)(ws);                          // 8 MB
  u16* w1t   = (u16*)(ws + 8388608ull);             // 64 MB  tiled [E][F/64][H/64][64][64]
  u16* w2t   = (u16*)(ws + 75497472ull);            // 64 MB  tiled [E][H/64][F/64][64][64]
  u16* hbuf  = (u16*)(ws + 142606336ull);           // 64 MB  [8192][F] bf16
  // ybuf reuses w1t's 64MB region: w1t is dead after gemm1, ybuf written by gemm2.
  float* ybuf = (float*)(ws + 8388608ull);          // 64 MB  2 slabs of [8192][H] f32
  int*   tki    = (int*)(ws + 209715200ull);
  float* tkw    = (float*)(ws + 209747968ull);
  int*   perm   = (int*)(ws + 209780736ull);
  float* pw     = (float*)(ws + 209813504ull);
  int*   counts = (int*)(ws + 209846272ull);        // counts[8], cursor[8], zsum
  int*   cursor = counts + 8;
  float* zsum   = (float*)(counts + 16);
  int*   islot  = (int*)(ws + 209846400ull);        // 32 KB  [T][2] slot map

  hipMemsetAsync(counts, 0, 128, stream);

  // prep: router (0..255) + W1 strips (256..2303). W2 transpose rides inside gemm1.
  prep_kernel<<<2304, 256, 0, stream>>>(x, Wr, br, xb, tki, tkw, counts, zsum, W1, w1t);
  scatter_kernel<<<T_TOK / 256, 256, 0, stream>>>(tki, tkw, counts, cursor, perm, pw,
                                                  islot, zsum, out + OUT_ELEMS);
  // gemm1: 2048 gemm blocks (8e x 16n x 16m, 256^2 tiles) + 2048 W2-transpose strips
  gemm1_kernel<<<4096, 512, 0, stream>>>(xb, w1t, b1, perm, counts, hbuf, W2, w2t);
  // gemm2: 8e x 4n x 2ks x 16m
  gemm2_kernel<<<1024, 512, 0, stream>>>(hbuf, w2t, b2, pw, counts, ybuf);
  combine_kernel<<<T_TOK, 256, 0, stream>>>(ybuf, islot, out);
}